// Round 13
// baseline (58.672 us; speedup 1.0000x reference)
//
#include <hip/hip_runtime.h>

#define DYN 16
#define DON 256
#define DIN 256
#define BSN 4096
#define NF 4096   /* DY*DI feature rows */
#define KTOT 512  /* concat K = 2*DI */

typedef unsigned short u16;
typedef __attribute__((ext_vector_type(8))) short bf16x8;
typedef __attribute__((ext_vector_type(4))) float f32x4;
typedef __attribute__((ext_vector_type(4))) unsigned short u16x4;

static __device__ __forceinline__ u16 f2bf(float f) {
  unsigned u = __builtin_bit_cast(unsigned, f);
  u += 0x7fffu + ((u >> 16) & 1u);
  return (u16)(u >> 16);
}
static __device__ __forceinline__ float bf2f(u16 h) {
  unsigned u = ((unsigned)h) << 16;
  return __builtin_bit_cast(float, u);
}

// ---------------------------------------------------------------------------
// Kernel 1 (fused pre-pass, 2048 blocks):
//  blocks 0..1023: fold rms into weights, concat [Wu | Wl(rev-rms)], bf16.
//  blocks 1024..2047: 128x128 tiled transpose of x w/ f32->bf16 + per-column
//    sum(x^2) partials. xbf: [4096 b][4096 f], f contiguous. partial: [32][BS].
// ---------------------------------------------------------------------------
__global__ __launch_bounds__(256) void k_pre(
    const float* __restrict__ x, const float* __restrict__ wu,
    const float* __restrict__ wl, const float* __restrict__ rms,
    u16* __restrict__ aprep, u16* __restrict__ xbf,
    float* __restrict__ partial) {
  __shared__ u16 tile[128 * 132];
  const int t = threadIdx.x;
  if (blockIdx.x < 1024) {
    int e = blockIdx.x * 256 + t;
    int row = e >> 6;
    int k0 = (e & 63) << 3;
    int d = row >> 8;
    const float* src;
    const float* rp;
    if (k0 < 256) {
      src = wu + (size_t)row * 256 + k0;
      rp  = rms + d * 256 + k0;
    } else {
      src = wl + (size_t)row * 256 + (k0 - 256);
      rp  = rms + (DYN - 1 - d) * 256 + (k0 - 256);
    }
    float4 s0 = *reinterpret_cast<const float4*>(src);
    float4 s1 = *reinterpret_cast<const float4*>(src + 4);
    float4 r0 = *reinterpret_cast<const float4*>(rp);
    float4 r1 = *reinterpret_cast<const float4*>(rp + 4);
    bf16x8 o;
    o[0] = (short)f2bf(s0.x * r0.x); o[1] = (short)f2bf(s0.y * r0.y);
    o[2] = (short)f2bf(s0.z * r0.z); o[3] = (short)f2bf(s0.w * r0.w);
    o[4] = (short)f2bf(s1.x * r1.x); o[5] = (short)f2bf(s1.y * r1.y);
    o[6] = (short)f2bf(s1.z * r1.z); o[7] = (short)f2bf(s1.w * r1.w);
    *reinterpret_cast<bf16x8*>(aprep + (size_t)row * KTOT + k0) = o;
    return;
  }
  const int bid = blockIdx.x - 1024;
  const int bt = bid & 31, ft = bid >> 5;
  const float* xb = x + (size_t)ft * 128 * BSN + bt * 128;
  const int frow = t >> 5, b4 = (t & 31) * 4;
  #pragma unroll
  for (int p = 0; p < 16; ++p) {
    int f = p * 8 + frow;
    float4 v = *reinterpret_cast<const float4*>(xb + (size_t)f * BSN + b4);
    u16x4 h;
    h[0] = f2bf(v.x); h[1] = f2bf(v.y); h[2] = f2bf(v.z); h[3] = f2bf(v.w);
    *reinterpret_cast<u16x4*>(&tile[f * 132 + b4]) = h;
  }
  __syncthreads();
  const int chunk = t & 15;
  const int bg = t >> 4;
  #pragma unroll
  for (int p = 0; p < 8; ++p) {
    int b = bg + p * 16;
    float s = 0.f;
    bf16x8 w;
    #pragma unroll
    for (int jj = 0; jj < 8; ++jj) {
      int j = (jj + chunk) & 7;
      u16 v = tile[(chunk * 8 + j) * 132 + b];
      float xv = bf2f(v);
      s += xv * xv;
      w[j] = (short)v;
    }
    *reinterpret_cast<bf16x8*>(
        xbf + (size_t)(bt * 128 + b) * NF + ft * 128 + chunk * 8) = w;
    #pragma unroll
    for (int m = 1; m < 16; m <<= 1) s += __shfl_xor(s, m, 64);
    if (chunk == 0) partial[ft * BSN + bt * 128 + b] = s;
  }
}

// ---------------------------------------------------------------------------
// Kernel 2: dual-sequential-tile bf16 MFMA GEMM with store-overlap.
// 256 blocks = 1/CU, 8 waves (2M batch x 4N feat). Block = 256 batches x
// 256 features of one d, computed as TWO sequential 256x128 tiles sharing
// identical A (x) data. Tile-1's epilogue (16 float4/thread, acc1 folded
// into regs) is stored 1 float4 PER K-STEP during tile-2's K-loop -> the
// ~9.4us serial store burst (64MB fp32, measured BW-bound in R11) half-
// overlaps under compute. vmcnt is position-based (issue-order retire):
// per-kt gate = newer-than-L(kt+1) = {1 store + 3 stage loads} -> vmcnt(4)
// (loop2) / vmcnt(3) (loop1); kt14 -> vmcnt(1)/vmcnt(0).
// K-loop is #pragma unroll'd so e1[kt] is STATICALLY indexed (rule #20:
// runtime-indexed reg arrays demote to scratch).
// 3-slot ring (A 16KB + B 8KB per slot), R5-proven WAR discipline; barrier
// between loops covers slot restage WAR. Involution swizzle (R2 measured
// zero-conflict) at pre-swizzled gload source + XOR'd ds_read. fc folded in
// prologue; XCD map bid&7 = d-pair.
// ---------------------------------------------------------------------------
__global__ __launch_bounds__(512, 2) void k_gemm(
    const u16* __restrict__ aprep, const u16* __restrict__ xbf,
    const float* __restrict__ partial, const float* __restrict__ bias,
    float* __restrict__ out) {
  extern __shared__ char smem[];
  float* fcl = (float*)(smem + 73728);       // 256 floats
  const int bid = blockIdx.x;
  const int dp = bid & 7;                    // d-pair -> XCD
  const int d = ((bid >> 3) & 1) ? (15 - dp) : dp;
  const int bt = bid >> 4;                   // 0..15 batch tile
  const int b0 = bt * 256;
  const int t = threadIdx.x;
  const int wave = t >> 6, lane = t & 63;
  const int lhi = lane >> 4, llo = lane & 15;
  const int wm = wave >> 2, wn = wave & 3;   // 2 batch-halves x 4 f-quarters
  const int kmask = ((llo >> 1) & 7) << 4;

  // stage one K-step into ring slot: A (x, 2 loads) + B (weights, 1 load)
  auto stage = [&](int slot, int kt, int frL) {
    const int fbase = (kt < 8) ? (d * 256 + kt * 32)
                               : ((15 - d) * 256 + (kt - 8) * 32);
    #pragma unroll
    for (int j = 0; j < 2; ++j) {
      int c = j * 512 + t;
      int cl = c ^ ((c >> 3) & 7);
      int r = cl >> 2, kc = cl & 3;
      const u16* g = xbf + (size_t)(b0 + r) * NF + fbase + kc * 8;
      unsigned lbase = (unsigned)(slot * 24576 + (j * 512 + wave * 64) * 16);
      __builtin_amdgcn_global_load_lds(
          (const __attribute__((address_space(1))) unsigned int*)g,
          (__attribute__((address_space(3))) unsigned int*)(smem + lbase),
          16, 0, 0);
    }
    {
      int c = t;                        // 512 chunks for the 8KB B tile
      int cl = c ^ ((c >> 3) & 7);
      int r = cl >> 2, kc = cl & 3;     // r in 0..127
      const u16* g = aprep + (size_t)(frL + r) * KTOT + kt * 32 + kc * 8;
      unsigned lbase = (unsigned)(slot * 24576 + 16384 + (wave * 64) * 16);
      __builtin_amdgcn_global_load_lds(
          (const __attribute__((address_space(1))) unsigned int*)g,
          (__attribute__((address_space(3))) unsigned int*)(smem + lbase),
          16, 0, 0);
    }
  };

  // fc for this block's 256 batches (loads precede stages; gates over-wait
  // them harmlessly in the prologue)
  if (t < 256) {
    float fs = 0.f;
    #pragma unroll
    for (int i = 0; i < 32; ++i) fs += partial[i * BSN + b0 + t];
    fcl[t] = rsqrtf(fs * (1.0f / 4096.0f) + 1e-6f);
  }

  f32x4 acc[8][2];
  float4 e1[16];                 // tile-1 epilogue values held across loop-2

  #pragma unroll
  for (int L = 0; L < 2; ++L) {
    const int frL = d * 256 + L * 128;   // this tile's feature base
    #pragma unroll
    for (int m = 0; m < 8; ++m)
      #pragma unroll
      for (int n = 0; n < 2; ++n)
        acc[m][n] = f32x4{0.f, 0.f, 0.f, 0.f};

    stage(0, 0, frL);
    stage(1, 1, frL);
    asm volatile("s_waitcnt vmcnt(3)\n\ts_barrier" ::: "memory");

    #pragma unroll
    for (int kt = 0; kt < 16; ++kt) {
      const int slot = kt % 3;
      const char* sA = (const char*)smem + slot * 24576;
      const char* sB = sA + 16384;
      if (L == 1) {
        // dribble one tile-1 store per K-step (overlaps under this loop)
        int m = kt >> 1, n = kt & 1;
        size_t ob = (size_t)(d * 256 + wn * 32 + n * 16 + llo) * BSN +
                    b0 + wm * 128 + m * 16 + lhi * 4;
        *reinterpret_cast<float4*>(out + ob) = e1[kt];
      }
      if (kt < 14) stage((kt + 2) % 3, kt + 2, frL);

      bf16x8 af[8], bq[2];
      #pragma unroll
      for (int m = 0; m < 8; ++m) {
        int row = wm * 128 + m * 16 + llo;
        af[m] = *reinterpret_cast<const bf16x8*>(
            sA + ((row * 64 + lhi * 16) ^ kmask));
      }
      #pragma unroll
      for (int n = 0; n < 2; ++n) {
        int row = wn * 32 + n * 16 + llo;
        bq[n] = *reinterpret_cast<const bf16x8*>(
            sB + ((row * 64 + lhi * 16) ^ kmask));
      }
      __builtin_amdgcn_s_setprio(1);
      #pragma unroll
      for (int m = 0; m < 8; ++m)
        #pragma unroll
        for (int n = 0; n < 2; ++n)
          acc[m][n] = __builtin_amdgcn_mfma_f32_16x16x32_bf16(
              af[m], bq[n], acc[m][n], 0, 0, 0);
      __builtin_amdgcn_s_setprio(0);

      if (kt < 14) {
        if (L == 1) {
          asm volatile("s_waitcnt vmcnt(4)\n\ts_barrier" ::: "memory");
        } else {
          asm volatile("s_waitcnt vmcnt(3)\n\ts_barrier" ::: "memory");
        }
      } else if (kt == 14) {
        if (L == 1) {
          asm volatile("s_waitcnt vmcnt(1)\n\ts_barrier" ::: "memory");
        } else {
          asm volatile("s_waitcnt vmcnt(0)\n\ts_barrier" ::: "memory");
        }
      }
    }

    // epilogue compute: relu(fc[b]*acc + bias[f]) -> regs (L=0) / store (L=1)
    #pragma unroll
    for (int m = 0; m < 8; ++m) {
      int lb = wm * 128 + m * 16 + lhi * 4;
      float4 fq = *reinterpret_cast<const float4*>(&fcl[lb]);
      #pragma unroll
      for (int n = 0; n < 2; ++n) {
        int fo = frL + wn * 32 + n * 16 + llo;
        float bv = bias[fo];
        float4 v;
        v.x = fmaxf(acc[m][n][0] * fq.x + bv, 0.f);
        v.y = fmaxf(acc[m][n][1] * fq.y + bv, 0.f);
        v.z = fmaxf(acc[m][n][2] * fq.z + bv, 0.f);
        v.w = fmaxf(acc[m][n][3] * fq.w + bv, 0.f);
        if (L == 0) {
          e1[m * 2 + n] = v;
        } else {
          *reinterpret_cast<float4*>(
              out + (size_t)fo * BSN + b0 + lb) = v;
        }
      }
    }
    if (L == 0) __builtin_amdgcn_s_barrier();  // all slot reads done before restage
  }
}

extern "C" void kernel_launch(void* const* d_in, const int* in_sizes, int n_in,
                              void* d_out, int out_size, void* d_ws, size_t ws_size,
                              hipStream_t stream) {
  (void)in_sizes; (void)n_in; (void)out_size; (void)ws_size;
  const float* x    = (const float*)d_in[0];
  const float* rms  = (const float*)d_in[1];
  const float* wu   = (const float*)d_in[2];
  const float* wl   = (const float*)d_in[3];
  const float* bias = (const float*)d_in[4];
  float* out = (float*)d_out;

  char* ws = (char*)d_ws;
  u16* xbf      = (u16*)ws;                      // 32 MiB  (x^T bf16)
  u16* aprep    = (u16*)(ws + 33554432);         // 4 MiB   (folded weights)
  float* partial = (float*)(ws + 37748736);      // 512 KiB (sumsq partials)

  k_pre<<<2048, 256, 0, stream>>>(x, wu, wl, rms, aprep, xbf, partial);
  k_gemm<<<256, 512, 74752, stream>>>(aprep, xbf, partial, bias, out);
}

// Round 15
// 57.505 us; speedup vs baseline: 1.0203x; 1.0203x over previous
//
#include <hip/hip_runtime.h>

#define DYN 16
#define DON 256
#define DIN 256
#define BSN 4096
#define NF 4096   /* DY*DI feature rows */
#define KTOT 512  /* concat K = 2*DI */

typedef unsigned short u16;
typedef __attribute__((ext_vector_type(8))) short bf16x8;
typedef __attribute__((ext_vector_type(4))) float f32x4;
typedef __attribute__((ext_vector_type(4))) unsigned short u16x4;

static __device__ __forceinline__ u16 f2bf(float f) {
  unsigned u = __builtin_bit_cast(unsigned, f);
  u += 0x7fffu + ((u >> 16) & 1u);
  return (u16)(u >> 16);
}
static __device__ __forceinline__ float bf2f(u16 h) {
  unsigned u = ((unsigned)h) << 16;
  return __builtin_bit_cast(float, u);
}

// ---------------------------------------------------------------------------
// Kernel 1 (fused pre-pass, 2048 blocks):
//  blocks 0..1023: fold rms into weights, concat [Wu | Wl(rev-rms)], bf16.
//  blocks 1024..2047: 128x128 tiled transpose of x w/ f32->bf16 + per-column
//    sum(x^2) partials. xbf: [4096 b][4096 f], f contiguous. partial: [32][BS].
// ---------------------------------------------------------------------------
__global__ __launch_bounds__(256) void k_pre(
    const float* __restrict__ x, const float* __restrict__ wu,
    const float* __restrict__ wl, const float* __restrict__ rms,
    u16* __restrict__ aprep, u16* __restrict__ xbf,
    float* __restrict__ partial) {
  __shared__ u16 tile[128 * 132];
  const int t = threadIdx.x;
  if (blockIdx.x < 1024) {
    int e = blockIdx.x * 256 + t;
    int row = e >> 6;
    int k0 = (e & 63) << 3;
    int d = row >> 8;
    const float* src;
    const float* rp;
    if (k0 < 256) {
      src = wu + (size_t)row * 256 + k0;
      rp  = rms + d * 256 + k0;
    } else {
      src = wl + (size_t)row * 256 + (k0 - 256);
      rp  = rms + (DYN - 1 - d) * 256 + (k0 - 256);
    }
    float4 s0 = *reinterpret_cast<const float4*>(src);
    float4 s1 = *reinterpret_cast<const float4*>(src + 4);
    float4 r0 = *reinterpret_cast<const float4*>(rp);
    float4 r1 = *reinterpret_cast<const float4*>(rp + 4);
    bf16x8 o;
    o[0] = (short)f2bf(s0.x * r0.x); o[1] = (short)f2bf(s0.y * r0.y);
    o[2] = (short)f2bf(s0.z * r0.z); o[3] = (short)f2bf(s0.w * r0.w);
    o[4] = (short)f2bf(s1.x * r1.x); o[5] = (short)f2bf(s1.y * r1.y);
    o[6] = (short)f2bf(s1.z * r1.z); o[7] = (short)f2bf(s1.w * r1.w);
    *reinterpret_cast<bf16x8*>(aprep + (size_t)row * KTOT + k0) = o;
    return;
  }
  const int bid = blockIdx.x - 1024;
  const int bt = bid & 31, ft = bid >> 5;
  const float* xb = x + (size_t)ft * 128 * BSN + bt * 128;
  const int frow = t >> 5, b4 = (t & 31) * 4;
  #pragma unroll
  for (int p = 0; p < 16; ++p) {
    int f = p * 8 + frow;
    float4 v = *reinterpret_cast<const float4*>(xb + (size_t)f * BSN + b4);
    u16x4 h;
    h[0] = f2bf(v.x); h[1] = f2bf(v.y); h[2] = f2bf(v.z); h[3] = f2bf(v.w);
    *reinterpret_cast<u16x4*>(&tile[f * 132 + b4]) = h;
  }
  __syncthreads();
  const int chunk = t & 15;
  const int bg = t >> 4;
  #pragma unroll
  for (int p = 0; p < 8; ++p) {
    int b = bg + p * 16;
    float s = 0.f;
    bf16x8 w;
    #pragma unroll
    for (int jj = 0; jj < 8; ++jj) {
      int j = (jj + chunk) & 7;
      u16 v = tile[(chunk * 8 + j) * 132 + b];
      float xv = bf2f(v);
      s += xv * xv;
      w[j] = (short)v;
    }
    *reinterpret_cast<bf16x8*>(
        xbf + (size_t)(bt * 128 + b) * NF + ft * 128 + chunk * 8) = w;
    #pragma unroll
    for (int m = 1; m < 16; m <<= 1) s += __shfl_xor(s, m, 64);
    if (chunk == 0) partial[ft * BSN + bt * 128 + b] = s;
  }
}

// ---------------------------------------------------------------------------
// Kernel 2: bf16 MFMA GEMM, 256b x 128f tiles, 512 blocks, 2 BLOCKS/CU.
// Model (R13 post-mortem): R10's 32.6us = K-loop ~21 (at ~800 TF) +
// store burst ~9.4 (64MB fp32, globally serialized at 1 blk/CU lockstep) +
// prologue ~1.5. Fix: 2 co-resident blocks/CU desync naturally -> one
// block's epilogue/prologue hides under the partner's K-loop (m114
// cross-wave MFMA||VMEM overlap; the m97 mechanism). K-loop discipline is
// R10's, byte-identical: 3-slot LDS ring (A 16KB + B 8KB per slot),
// steady s_waitcnt vmcnt(3) (3 loads/stage, 2 stages in flight; never
// drains mid-loop), involution swizzle chunk^((chunk>>3)&7) at
// pre-swizzled gload source + XOR'd ds_read (R2 measured-zero-conflict),
// setprio(1) around MFMA clusters, fc folded in prologue, float4
// batch-contiguous epilogue (R8 silicon-verified C-layout).
// acc[8][2] = 64 VGPR -> fits 128-VGPR cap at 4 waves/EU (2 blk/CU).
// XCD map: bid&7 = d-pair. LDS 73KB x 2 blocks = 146KB <= 160KB.
// ---------------------------------------------------------------------------
__global__ __launch_bounds__(512, 4) void k_gemm(
    const u16* __restrict__ aprep, const u16* __restrict__ xbf,
    const float* __restrict__ partial, const float* __restrict__ bias,
    float* __restrict__ out) {
  extern __shared__ char smem[];
  float* fcl = (float*)(smem + 73728);       // 256 floats
  const int bid = blockIdx.x;
  const int dp = bid & 7;                    // d-pair -> XCD
  const int s = bid >> 3;
  const int d = (s & 1) ? (15 - dp) : dp;
  const int fh = (s >> 1) & 1;               // feature half of this d
  const int bt = s >> 2;                     // 0..15 batch tile
  const int b0 = bt * 256;
  const int fr0 = d * 256 + fh * 128;
  const int t = threadIdx.x;
  const int wave = t >> 6, lane = t & 63;
  const int lhi = lane >> 4, llo = lane & 15;
  const int wm = wave >> 2, wn = wave & 3;   // 2 batch-halves x 4 f-quarters
  const int kmask = ((llo >> 1) & 7) << 4;

  // stage one K-step: A (x, 2 loads, 16KB) + B (weights, 1 load, 8KB)
  auto stage = [&](int slot, int kt) {
    const int fbase = (kt < 8) ? (d * 256 + kt * 32)
                               : ((15 - d) * 256 + (kt - 8) * 32);
    #pragma unroll
    for (int j = 0; j < 2; ++j) {
      int c = j * 512 + t;              // physical 16B chunk (0..1023)
      int cl = c ^ ((c >> 3) & 7);      // logical chunk (involution)
      int r = cl >> 2, kc = cl & 3;     // batch row / k-octet
      const u16* g = xbf + (size_t)(b0 + r) * NF + fbase + kc * 8;
      unsigned lbase = (unsigned)(slot * 24576 + (j * 512 + wave * 64) * 16);
      __builtin_amdgcn_global_load_lds(
          (const __attribute__((address_space(1))) unsigned int*)g,
          (__attribute__((address_space(3))) unsigned int*)(smem + lbase),
          16, 0, 0);
    }
    {
      int c = t;                        // 512 chunks for the 8KB B tile
      int cl = c ^ ((c >> 3) & 7);
      int r = cl >> 2, kc = cl & 3;     // f row 0..127 / k-octet
      const u16* g = aprep + (size_t)(fr0 + r) * KTOT + kt * 32 + kc * 8;
      unsigned lbase = (unsigned)(slot * 24576 + 16384 + (wave * 64) * 16);
      __builtin_amdgcn_global_load_lds(
          (const __attribute__((address_space(1))) unsigned int*)g,
          (__attribute__((address_space(3))) unsigned int*)(smem + lbase),
          16, 0, 0);
    }
  };

  // fc for this block's 256 batches (overlaps staging latency)
  if (t < 256) {
    float fs = 0.f;
    #pragma unroll
    for (int i = 0; i < 32; ++i) fs += partial[i * BSN + b0 + t];
    fcl[t] = rsqrtf(fs * (1.0f / 4096.0f) + 1e-6f);
  }

  f32x4 acc[8][2];
  #pragma unroll
  for (int m = 0; m < 8; ++m)
    #pragma unroll
    for (int n = 0; n < 2; ++n)
      acc[m][n] = f32x4{0.f, 0.f, 0.f, 0.f};

  stage(0, 0);
  stage(1, 1);
  asm volatile("s_waitcnt vmcnt(3)\n\ts_barrier" ::: "memory");

  for (int kt = 0; kt < 16; ++kt) {
    const int slot = kt % 3;
    const char* sA = (const char*)smem + slot * 24576;
    const char* sB = sA + 16384;
    if (kt < 14) stage((kt + 2) % 3, kt + 2);

    bf16x8 bq[2], af[4];
    #pragma unroll
    for (int n = 0; n < 2; ++n) {
      int row = wn * 32 + n * 16 + llo;
      bq[n] = *reinterpret_cast<const bf16x8*>(
          sB + ((row * 64 + lhi * 16) ^ kmask));
    }
    // batch half 0
    #pragma unroll
    for (int m = 0; m < 4; ++m) {
      int row = wm * 128 + m * 16 + llo;
      af[m] = *reinterpret_cast<const bf16x8*>(
          sA + ((row * 64 + lhi * 16) ^ kmask));
    }
    __builtin_amdgcn_s_setprio(1);
    #pragma unroll
    for (int m = 0; m < 4; ++m)
      #pragma unroll
      for (int n = 0; n < 2; ++n)
        acc[m][n] = __builtin_amdgcn_mfma_f32_16x16x32_bf16(
            af[m], bq[n], acc[m][n], 0, 0, 0);
    __builtin_amdgcn_s_setprio(0);
    // batch half 1 (reuse af regs)
    #pragma unroll
    for (int m = 0; m < 4; ++m) {
      int row = wm * 128 + 64 + m * 16 + llo;
      af[m] = *reinterpret_cast<const bf16x8*>(
          sA + ((row * 64 + lhi * 16) ^ kmask));
    }
    __builtin_amdgcn_s_setprio(1);
    #pragma unroll
    for (int m = 0; m < 4; ++m)
      #pragma unroll
      for (int n = 0; n < 2; ++n)
        acc[4 + m][n] = __builtin_amdgcn_mfma_f32_16x16x32_bf16(
            af[m], bq[n], acc[4 + m][n], 0, 0, 0);
    __builtin_amdgcn_s_setprio(0);

    if (kt < 14) {
      asm volatile("s_waitcnt vmcnt(3)\n\ts_barrier" ::: "memory");
    } else if (kt == 14) {
      asm volatile("s_waitcnt vmcnt(0)\n\ts_barrier" ::: "memory");
    }
  }

  // epilogue: y[f][b] = relu(fc[b]*acc + bias[f]), float4 over batch
  #pragma unroll
  for (int m = 0; m < 8; ++m) {
    int lb = wm * 128 + m * 16 + lhi * 4;
    float4 fq = *reinterpret_cast<const float4*>(&fcl[lb]);
    #pragma unroll
    for (int n = 0; n < 2; ++n) {
      int fo = fr0 + wn * 32 + n * 16 + llo;
      float bv = bias[fo];
      float4 v;
      v.x = fmaxf(acc[m][n][0] * fq.x + bv, 0.f);
      v.y = fmaxf(acc[m][n][1] * fq.y + bv, 0.f);
      v.z = fmaxf(acc[m][n][2] * fq.z + bv, 0.f);
      v.w = fmaxf(acc[m][n][3] * fq.w + bv, 0.f);
      *reinterpret_cast<float4*>(out + (size_t)fo * BSN + b0 + lb) = v;
    }
  }
}

extern "C" void kernel_launch(void* const* d_in, const int* in_sizes, int n_in,
                              void* d_out, int out_size, void* d_ws, size_t ws_size,
                              hipStream_t stream) {
  (void)in_sizes; (void)n_in; (void)out_size; (void)ws_size;
  const float* x    = (const float*)d_in[0];
  const float* rms  = (const float*)d_in[1];
  const float* wu   = (const float*)d_in[2];
  const float* wl   = (const float*)d_in[3];
  const float* bias = (const float*)d_in[4];
  float* out = (float*)d_out;

  char* ws = (char*)d_ws;
  u16* xbf      = (u16*)ws;                      // 32 MiB  (x^T bf16)
  u16* aprep    = (u16*)(ws + 33554432);         // 4 MiB   (folded weights)
  float* partial = (float*)(ws + 37748736);      // 512 KiB (sumsq partials)

  k_pre<<<2048, 256, 0, stream>>>(x, wu, wl, rms, aprep, xbf, partial);
  k_gemm<<<512, 512, 74752, stream>>>(aprep, xbf, partial, bias, out);
}

// Round 18
// 54.711 us; speedup vs baseline: 1.0724x; 1.0511x over previous
//
#include <hip/hip_runtime.h>

#define DYN 16
#define DON 256
#define DIN 256
#define BSN 4096
#define NF 4096   /* DY*DI feature rows */
#define KTOT 512  /* concat K = 2*DI */

typedef unsigned short u16;
typedef __attribute__((ext_vector_type(8))) short bf16x8;
typedef __attribute__((ext_vector_type(4))) float f32x4;
typedef __attribute__((ext_vector_type(4))) unsigned short u16x4;

static __device__ __forceinline__ u16 f2bf(float f) {
  unsigned u = __builtin_bit_cast(unsigned, f);
  u += 0x7fffu + ((u >> 16) & 1u);
  return (u16)(u >> 16);
}
static __device__ __forceinline__ float bf2f(u16 h) {
  unsigned u = ((unsigned)h) << 16;
  return __builtin_bit_cast(float, u);
}

// ---------------------------------------------------------------------------
// Kernel 1 (fused pre-pass, 2048 blocks):
//  blocks 0..1023: fold rms into weights, concat [Wu | Wl(rev-rms)], bf16.
//  blocks 1024..2047: 128x128 tiled transpose of x w/ f32->bf16 + per-column
//    sum(x^2) partials. xbf: [4096 b][4096 f], f contiguous. partial: [32][BS].
// ---------------------------------------------------------------------------
__global__ __launch_bounds__(256) void k_pre(
    const float* __restrict__ x, const float* __restrict__ wu,
    const float* __restrict__ wl, const float* __restrict__ rms,
    u16* __restrict__ aprep, u16* __restrict__ xbf,
    float* __restrict__ partial) {
  __shared__ u16 tile[128 * 132];
  const int t = threadIdx.x;
  if (blockIdx.x < 1024) {
    int e = blockIdx.x * 256 + t;
    int row = e >> 6;
    int k0 = (e & 63) << 3;
    int d = row >> 8;
    const float* src;
    const float* rp;
    if (k0 < 256) {
      src = wu + (size_t)row * 256 + k0;
      rp  = rms + d * 256 + k0;
    } else {
      src = wl + (size_t)row * 256 + (k0 - 256);
      rp  = rms + (DYN - 1 - d) * 256 + (k0 - 256);
    }
    float4 s0 = *reinterpret_cast<const float4*>(src);
    float4 s1 = *reinterpret_cast<const float4*>(src + 4);
    float4 r0 = *reinterpret_cast<const float4*>(rp);
    float4 r1 = *reinterpret_cast<const float4*>(rp + 4);
    bf16x8 o;
    o[0] = (short)f2bf(s0.x * r0.x); o[1] = (short)f2bf(s0.y * r0.y);
    o[2] = (short)f2bf(s0.z * r0.z); o[3] = (short)f2bf(s0.w * r0.w);
    o[4] = (short)f2bf(s1.x * r1.x); o[5] = (short)f2bf(s1.y * r1.y);
    o[6] = (short)f2bf(s1.z * r1.z); o[7] = (short)f2bf(s1.w * r1.w);
    *reinterpret_cast<bf16x8*>(aprep + (size_t)row * KTOT + k0) = o;
    return;
  }
  const int bid = blockIdx.x - 1024;
  const int bt = bid & 31, ft = bid >> 5;
  const float* xb = x + (size_t)ft * 128 * BSN + bt * 128;
  const int frow = t >> 5, b4 = (t & 31) * 4;
  #pragma unroll
  for (int p = 0; p < 16; ++p) {
    int f = p * 8 + frow;
    float4 v = *reinterpret_cast<const float4*>(xb + (size_t)f * BSN + b4);
    u16x4 h;
    h[0] = f2bf(v.x); h[1] = f2bf(v.y); h[2] = f2bf(v.z); h[3] = f2bf(v.w);
    *reinterpret_cast<u16x4*>(&tile[f * 132 + b4]) = h;
  }
  __syncthreads();
  const int chunk = t & 15;
  const int bg = t >> 4;
  #pragma unroll
  for (int p = 0; p < 8; ++p) {
    int b = bg + p * 16;
    float s = 0.f;
    bf16x8 w;
    #pragma unroll
    for (int jj = 0; jj < 8; ++jj) {
      int j = (jj + chunk) & 7;
      u16 v = tile[(chunk * 8 + j) * 132 + b];
      float xv = bf2f(v);
      s += xv * xv;
      w[j] = (short)v;
    }
    *reinterpret_cast<bf16x8*>(
        xbf + (size_t)(bt * 128 + b) * NF + ft * 128 + chunk * 8) = w;
    #pragma unroll
    for (int m = 1; m < 16; m <<= 1) s += __shfl_xor(s, m, 64);
    if (chunk == 0) partial[ft * BSN + bt * 128 + b] = s;
  }
}

// ---------------------------------------------------------------------------
// Kernel 2: 4-phase bf16 MFMA GEMM (R10 config - session best, 54.7us).
// 256 blocks = 1/CU: block = 256 batches (M, A=x) x 256 features of one d
// (N, B=W). 8 waves (2 batch-halves x 4 feature-quarters), wave tile 128x64.
// BK=32 -> 16 K-steps. 3-slot 32KB LDS ring (96KB), WAR-safe since R5.
// Per K-step 4 phases: {ds_read subtile || 1 staging gload(kt+2)} ->
// s_barrier -> setprio(1) 8 MFMA setprio(0) -> s_barrier. B-frags register-
// cached across phases. Boundary wait once per K-step: s_waitcnt vmcnt(4)
// (4 loads/K-step/thread, 2 K-steps in flight) - never drains mid-loop.
// XCD map: bid&7 = d-pair -> per-XCD x-slice 4MB + W 0.5MB = L2-fit; the
// d/15-d pair (identical x bytes) is co-XCD. Involution swizzle (pre-
// swizzled gload source + XOR'd ds_read; R2-verified zero-conflict).
// fc folded in prologue. Epilogue: float4 batch-contiguous stores,
// relu(fc[b]*acc + bias[f]) (R8 silicon-verified C-layout).
// ---------------------------------------------------------------------------
__global__ __launch_bounds__(512, 2) void k_gemm(
    const u16* __restrict__ aprep, const u16* __restrict__ xbf,
    const float* __restrict__ partial, const float* __restrict__ bias,
    float* __restrict__ out) {
  extern __shared__ char smem[];
  float* fcl = (float*)(smem + 98304);       // 256 floats
  const int bid = blockIdx.x;
  const int dp = bid & 7;                    // d-pair -> XCD
  const int d = ((bid >> 3) & 1) ? (15 - dp) : dp;
  const int bt = bid >> 4;                   // 0..15 batch tile
  const int b0 = bt * 256;
  const int fr0 = d * 256;
  const int t = threadIdx.x;
  const int wave = t >> 6, lane = t & 63;
  const int lhi = lane >> 4, llo = lane & 15;
  const int wm = wave >> 2, wn = wave & 3;   // batch half / feature quarter
  const int kmask = ((llo >> 1) & 7) << 4;

  f32x4 acc[8][4] = {};

  // staging: op 0/1 = A(x) chunk j, op 2/3 = B(W) chunk j-2
  auto stage1 = [&](int slot, int kt, int op) {
    int j = op & 1;
    int c = j * 512 + t;                 // physical 16B chunk (0..1023)
    int cl = c ^ ((c >> 3) & 7);         // logical chunk (involution)
    int r = cl >> 2, kc = cl & 3;
    unsigned lbase = (unsigned)(slot * 32768 + (op >= 2 ? 16384 : 0) +
                                (j * 512 + wave * 64) * 16);
    const u16* g;
    if (op < 2) {
      int fbase = (kt < 8) ? (d * 256 + kt * 32)
                           : ((15 - d) * 256 + (kt - 8) * 32);
      g = xbf + (size_t)(b0 + r) * NF + fbase + kc * 8;
    } else {
      g = aprep + (size_t)(fr0 + r) * KTOT + kt * 32 + kc * 8;
    }
    __builtin_amdgcn_global_load_lds(
        (const __attribute__((address_space(1))) unsigned int*)g,
        (__attribute__((address_space(3))) unsigned int*)(smem + lbase),
        16, 0, 0);
  };
  auto stageK = [&](int slot, int kt) {
    #pragma unroll
    for (int op = 0; op < 4; ++op) stage1(slot, kt, op);
  };

  // fc for this block's 256 batches (overlaps staging latency)
  if (t < 256) {
    float fs = 0.f;
    #pragma unroll
    for (int i = 0; i < 32; ++i) fs += partial[i * BSN + b0 + t];
    fcl[t] = rsqrtf(fs * (1.0f / 4096.0f) + 1e-6f);
  }
  stageK(0, 0);
  stageK(1, 1);
  asm volatile("s_waitcnt vmcnt(4)\n\ts_barrier" ::: "memory");

  for (int kt = 0; kt < 16; ++kt) {
    const int slot = kt % 3;
    const char* sA = (const char*)smem + slot * 32768;
    const char* sB = sA + 16384;
    const int st_slot = (kt + 2) % 3;
    const bool do_st = kt < 14;
    bf16x8 af[4], bf0[2], bf1[2];

    // ---- phase 0: af(batch half 0) + bf0 ; stage A j=0
    #pragma unroll
    for (int i = 0; i < 4; ++i) {
      int row = wm * 128 + i * 16 + llo;
      af[i] = *reinterpret_cast<const bf16x8*>(sA + ((row * 64 + lhi * 16) ^ kmask));
    }
    #pragma unroll
    for (int j = 0; j < 2; ++j) {
      int row = wn * 64 + j * 16 + llo;
      bf0[j] = *reinterpret_cast<const bf16x8*>(sB + ((row * 64 + lhi * 16) ^ kmask));
    }
    if (do_st) stage1(st_slot, kt + 2, 0);
    asm volatile("" ::: "memory");
    __builtin_amdgcn_s_barrier();
    __builtin_amdgcn_s_setprio(1);
    #pragma unroll
    for (int i = 0; i < 4; ++i)
      #pragma unroll
      for (int j = 0; j < 2; ++j)
        acc[i][j] = __builtin_amdgcn_mfma_f32_16x16x32_bf16(af[i], bf0[j], acc[i][j], 0, 0, 0);
    __builtin_amdgcn_s_setprio(0);
    asm volatile("" ::: "memory");
    __builtin_amdgcn_s_barrier();

    // ---- phase 1: bf1 ; stage A j=1
    #pragma unroll
    for (int j = 0; j < 2; ++j) {
      int row = wn * 64 + 32 + j * 16 + llo;
      bf1[j] = *reinterpret_cast<const bf16x8*>(sB + ((row * 64 + lhi * 16) ^ kmask));
    }
    if (do_st) stage1(st_slot, kt + 2, 1);
    asm volatile("" ::: "memory");
    __builtin_amdgcn_s_barrier();
    __builtin_amdgcn_s_setprio(1);
    #pragma unroll
    for (int i = 0; i < 4; ++i)
      #pragma unroll
      for (int j = 0; j < 2; ++j)
        acc[i][2 + j] = __builtin_amdgcn_mfma_f32_16x16x32_bf16(af[i], bf1[j], acc[i][2 + j], 0, 0, 0);
    __builtin_amdgcn_s_setprio(0);
    asm volatile("" ::: "memory");
    __builtin_amdgcn_s_barrier();

    // ---- phase 2: af(batch half 1) ; stage B j=0
    #pragma unroll
    for (int i = 0; i < 4; ++i) {
      int row = wm * 128 + 64 + i * 16 + llo;
      af[i] = *reinterpret_cast<const bf16x8*>(sA + ((row * 64 + lhi * 16) ^ kmask));
    }
    if (do_st) stage1(st_slot, kt + 2, 2);
    asm volatile("" ::: "memory");
    __builtin_amdgcn_s_barrier();
    __builtin_amdgcn_s_setprio(1);
    #pragma unroll
    for (int i = 0; i < 4; ++i)
      #pragma unroll
      for (int j = 0; j < 2; ++j)
        acc[4 + i][j] = __builtin_amdgcn_mfma_f32_16x16x32_bf16(af[i], bf0[j], acc[4 + i][j], 0, 0, 0);
    __builtin_amdgcn_s_setprio(0);
    asm volatile("" ::: "memory");
    __builtin_amdgcn_s_barrier();

    // ---- phase 3: (no ds_read) ; stage B j=1 ; boundary wait
    if (do_st) stage1(st_slot, kt + 2, 3);
    __builtin_amdgcn_s_setprio(1);
    #pragma unroll
    for (int i = 0; i < 4; ++i)
      #pragma unroll
      for (int j = 0; j < 2; ++j)
        acc[4 + i][2 + j] = __builtin_amdgcn_mfma_f32_16x16x32_bf16(af[i], bf1[j], acc[4 + i][2 + j], 0, 0, 0);
    __builtin_amdgcn_s_setprio(0);
    if (kt < 14) {
      asm volatile("s_waitcnt vmcnt(4)\n\ts_barrier" ::: "memory");
    } else if (kt == 14) {
      asm volatile("s_waitcnt vmcnt(0)\n\ts_barrier" ::: "memory");
    }
  }

  // ---- epilogue: y[f][b] = relu(fc[b]*acc + bias[f]), float4 over batch
  #pragma unroll
  for (int m = 0; m < 8; ++m) {
    int lb = wm * 128 + m * 16 + lhi * 4;
    float4 fq = *reinterpret_cast<const float4*>(&fcl[lb]);
    #pragma unroll
    for (int n = 0; n < 4; ++n) {
      int fo = fr0 + wn * 64 + n * 16 + llo;
      float bv = bias[fo];
      float4 v;
      v.x = fmaxf(acc[m][n][0] * fq.x + bv, 0.f);
      v.y = fmaxf(acc[m][n][1] * fq.y + bv, 0.f);
      v.z = fmaxf(acc[m][n][2] * fq.z + bv, 0.f);
      v.w = fmaxf(acc[m][n][3] * fq.w + bv, 0.f);
      *reinterpret_cast<float4*>(out + (size_t)fo * BSN + b0 + lb) = v;
    }
  }
}

extern "C" void kernel_launch(void* const* d_in, const int* in_sizes, int n_in,
                              void* d_out, int out_size, void* d_ws, size_t ws_size,
                              hipStream_t stream) {
  (void)in_sizes; (void)n_in; (void)out_size; (void)ws_size;
  const float* x    = (const float*)d_in[0];
  const float* rms  = (const float*)d_in[1];
  const float* wu   = (const float*)d_in[2];
  const float* wl   = (const float*)d_in[3];
  const float* bias = (const float*)d_in[4];
  float* out = (float*)d_out;

  char* ws = (char*)d_ws;
  u16* xbf      = (u16*)ws;                      // 32 MiB  (x^T bf16)
  u16* aprep    = (u16*)(ws + 33554432);         // 4 MiB   (folded weights)
  float* partial = (float*)(ws + 37748736);      // 512 KiB (sumsq partials)

  k_pre<<<2048, 256, 0, stream>>>(x, wu, wl, rms, aprep, xbf, partial);
  k_gemm<<<256, 512, 99328, stream>>>(aprep, xbf, partial, bias, out);
}

// Round 19
// 50.332 us; speedup vs baseline: 1.1657x; 1.0870x over previous
//
#include <hip/hip_runtime.h>

#define DYN 16
#define DON 256
#define DIN 256
#define BSN 4096
#define NF 4096   /* DY*DI feature rows */
#define KTOT 512  /* concat K = 2*DI */

typedef unsigned short u16;
typedef __attribute__((ext_vector_type(8))) short bf16x8;
typedef __attribute__((ext_vector_type(4))) float f32x4;
typedef __attribute__((ext_vector_type(4))) unsigned short u16x4;

static __device__ __forceinline__ u16 f2bf(float f) {
  unsigned u = __builtin_bit_cast(unsigned, f);
  u += 0x7fffu + ((u >> 16) & 1u);
  return (u16)(u >> 16);
}
static __device__ __forceinline__ float bf2f(u16 h) {
  unsigned u = ((unsigned)h) << 16;
  return __builtin_bit_cast(float, u);
}

// ---------------------------------------------------------------------------
// Kernel 1 (fused pre-pass, 2048 blocks):
//  blocks 0..1023: fold rms into weights, concat [Wu | Wl(rev-rms)], bf16.
//  blocks 1024..2047: 128x128 tiled transpose of x w/ f32->bf16 + per-column
//    sum(x^2) partials. xbf: [4096 b][4096 f], f contiguous. partial: [32][BS].
//  LDS tile XOR swizzle: column b of row f stored at b ^ ((f>>3)<<2).
//  Write side: f>>3 = p constant per instr -> banking unchanged, 8B align ok.
//  Read side: r>>3 = chunk -> bank = 16(chunk&1)+2j+((b>>1)^(chunk<<1));
//  chunk-bijection spreads 16 chunks over 16 even banks, bg-parity fills the
//  odd banks -> 2-way (free, m136) vs the old stagger's 4-way (1.58x).
// ---------------------------------------------------------------------------
__global__ __launch_bounds__(256) void k_pre(
    const float* __restrict__ x, const float* __restrict__ wu,
    const float* __restrict__ wl, const float* __restrict__ rms,
    u16* __restrict__ aprep, u16* __restrict__ xbf,
    float* __restrict__ partial) {
  __shared__ u16 tile[128 * 132];
  const int t = threadIdx.x;
  if (blockIdx.x < 1024) {
    int e = blockIdx.x * 256 + t;
    int row = e >> 6;
    int k0 = (e & 63) << 3;
    int d = row >> 8;
    const float* src;
    const float* rp;
    if (k0 < 256) {
      src = wu + (size_t)row * 256 + k0;
      rp  = rms + d * 256 + k0;
    } else {
      src = wl + (size_t)row * 256 + (k0 - 256);
      rp  = rms + (DYN - 1 - d) * 256 + (k0 - 256);
    }
    float4 s0 = *reinterpret_cast<const float4*>(src);
    float4 s1 = *reinterpret_cast<const float4*>(src + 4);
    float4 r0 = *reinterpret_cast<const float4*>(rp);
    float4 r1 = *reinterpret_cast<const float4*>(rp + 4);
    bf16x8 o;
    o[0] = (short)f2bf(s0.x * r0.x); o[1] = (short)f2bf(s0.y * r0.y);
    o[2] = (short)f2bf(s0.z * r0.z); o[3] = (short)f2bf(s0.w * r0.w);
    o[4] = (short)f2bf(s1.x * r1.x); o[5] = (short)f2bf(s1.y * r1.y);
    o[6] = (short)f2bf(s1.z * r1.z); o[7] = (short)f2bf(s1.w * r1.w);
    *reinterpret_cast<bf16x8*>(aprep + (size_t)row * KTOT + k0) = o;
    return;
  }
  const int bid = blockIdx.x - 1024;
  const int bt = bid & 31, ft = bid >> 5;
  const float* xb = x + (size_t)ft * 128 * BSN + bt * 128;
  const int frow = t >> 5, b4 = (t & 31) * 4;
  #pragma unroll
  for (int p = 0; p < 16; ++p) {
    int f = p * 8 + frow;
    float4 v = *reinterpret_cast<const float4*>(xb + (size_t)f * BSN + b4);
    u16x4 h;
    h[0] = f2bf(v.x); h[1] = f2bf(v.y); h[2] = f2bf(v.z); h[3] = f2bf(v.w);
    *reinterpret_cast<u16x4*>(&tile[f * 132 + (b4 ^ ((f >> 3) << 2))]) = h;
  }
  __syncthreads();
  const int chunk = t & 15;
  const int bg = t >> 4;
  #pragma unroll
  for (int p = 0; p < 8; ++p) {
    int b = bg + p * 16;
    float s = 0.f;
    bf16x8 w;
    #pragma unroll
    for (int j = 0; j < 8; ++j) {
      int r = chunk * 8 + j;
      u16 v = tile[r * 132 + (b ^ ((r >> 3) << 2))];
      float xv = bf2f(v);
      s += xv * xv;
      w[j] = (short)v;
    }
    *reinterpret_cast<bf16x8*>(
        xbf + (size_t)(bt * 128 + b) * NF + ft * 128 + chunk * 8) = w;
    #pragma unroll
    for (int m = 1; m < 16; m <<= 1) s += __shfl_xor(s, m, 64);
    if (chunk == 0) partial[ft * BSN + bt * 128 + b] = s;
  }
}

// ---------------------------------------------------------------------------
// Kernel 2: 4-phase bf16 MFMA GEMM (R10 config - session best, 54.7us,
// reproduced R18). 256 blocks = 1/CU: block = 256 batches (M, A=x) x 256
// features of one d (N, B=W). 8 waves (2 batch-halves x 4 feature-quarters),
// wave tile 128x64. BK=32 -> 16 K-steps. 3-slot 32KB LDS ring (96KB).
// Per K-step 4 phases: {ds_read subtile || 1 staging gload(kt+2)} ->
// s_barrier -> setprio(1) 8 MFMA setprio(0) -> s_barrier. B-frags register-
// cached across phases. Boundary wait once per K-step: s_waitcnt vmcnt(4)
// (4 loads/K-step/thread, 2 K-steps in flight) - never drains mid-loop.
// XCD map: bid&7 = d-pair -> per-XCD x-slice 4MB + W 0.5MB = L2-fit.
// Involution swizzle (pre-swizzled gload source + XOR'd ds_read;
// R2-verified zero-conflict). fc folded in prologue. Epilogue: float4
// batch-contiguous stores, relu(fc[b]*acc + bias[f]).
// ---------------------------------------------------------------------------
__global__ __launch_bounds__(512, 2) void k_gemm(
    const u16* __restrict__ aprep, const u16* __restrict__ xbf,
    const float* __restrict__ partial, const float* __restrict__ bias,
    float* __restrict__ out) {
  extern __shared__ char smem[];
  float* fcl = (float*)(smem + 98304);       // 256 floats
  const int bid = blockIdx.x;
  const int dp = bid & 7;                    // d-pair -> XCD
  const int d = ((bid >> 3) & 1) ? (15 - dp) : dp;
  const int bt = bid >> 4;                   // 0..15 batch tile
  const int b0 = bt * 256;
  const int fr0 = d * 256;
  const int t = threadIdx.x;
  const int wave = t >> 6, lane = t & 63;
  const int lhi = lane >> 4, llo = lane & 15;
  const int wm = wave >> 2, wn = wave & 3;   // batch half / feature quarter
  const int kmask = ((llo >> 1) & 7) << 4;

  f32x4 acc[8][4] = {};

  // staging: op 0/1 = A(x) chunk j, op 2/3 = B(W) chunk j-2
  auto stage1 = [&](int slot, int kt, int op) {
    int j = op & 1;
    int c = j * 512 + t;                 // physical 16B chunk (0..1023)
    int cl = c ^ ((c >> 3) & 7);         // logical chunk (involution)
    int r = cl >> 2, kc = cl & 3;
    unsigned lbase = (unsigned)(slot * 32768 + (op >= 2 ? 16384 : 0) +
                                (j * 512 + wave * 64) * 16);
    const u16* g;
    if (op < 2) {
      int fbase = (kt < 8) ? (d * 256 + kt * 32)
                           : ((15 - d) * 256 + (kt - 8) * 32);
      g = xbf + (size_t)(b0 + r) * NF + fbase + kc * 8;
    } else {
      g = aprep + (size_t)(fr0 + r) * KTOT + kt * 32 + kc * 8;
    }
    __builtin_amdgcn_global_load_lds(
        (const __attribute__((address_space(1))) unsigned int*)g,
        (__attribute__((address_space(3))) unsigned int*)(smem + lbase),
        16, 0, 0);
  };
  auto stageK = [&](int slot, int kt) {
    #pragma unroll
    for (int op = 0; op < 4; ++op) stage1(slot, kt, op);
  };

  // fc for this block's 256 batches (overlaps staging latency)
  if (t < 256) {
    float fs = 0.f;
    #pragma unroll
    for (int i = 0; i < 32; ++i) fs += partial[i * BSN + b0 + t];
    fcl[t] = rsqrtf(fs * (1.0f / 4096.0f) + 1e-6f);
  }
  stageK(0, 0);
  stageK(1, 1);
  asm volatile("s_waitcnt vmcnt(4)\n\ts_barrier" ::: "memory");

  for (int kt = 0; kt < 16; ++kt) {
    const int slot = kt % 3;
    const char* sA = (const char*)smem + slot * 32768;
    const char* sB = sA + 16384;
    const int st_slot = (kt + 2) % 3;
    const bool do_st = kt < 14;
    bf16x8 af[4], bf0[2], bf1[2];

    // ---- phase 0: af(batch half 0) + bf0 ; stage A j=0
    #pragma unroll
    for (int i = 0; i < 4; ++i) {
      int row = wm * 128 + i * 16 + llo;
      af[i] = *reinterpret_cast<const bf16x8*>(sA + ((row * 64 + lhi * 16) ^ kmask));
    }
    #pragma unroll
    for (int j = 0; j < 2; ++j) {
      int row = wn * 64 + j * 16 + llo;
      bf0[j] = *reinterpret_cast<const bf16x8*>(sB + ((row * 64 + lhi * 16) ^ kmask));
    }
    if (do_st) stage1(st_slot, kt + 2, 0);
    asm volatile("" ::: "memory");
    __builtin_amdgcn_s_barrier();
    __builtin_amdgcn_s_setprio(1);
    #pragma unroll
    for (int i = 0; i < 4; ++i)
      #pragma unroll
      for (int j = 0; j < 2; ++j)
        acc[i][j] = __builtin_amdgcn_mfma_f32_16x16x32_bf16(af[i], bf0[j], acc[i][j], 0, 0, 0);
    __builtin_amdgcn_s_setprio(0);
    asm volatile("" ::: "memory");
    __builtin_amdgcn_s_barrier();

    // ---- phase 1: bf1 ; stage A j=1
    #pragma unroll
    for (int j = 0; j < 2; ++j) {
      int row = wn * 64 + 32 + j * 16 + llo;
      bf1[j] = *reinterpret_cast<const bf16x8*>(sB + ((row * 64 + lhi * 16) ^ kmask));
    }
    if (do_st) stage1(st_slot, kt + 2, 1);
    asm volatile("" ::: "memory");
    __builtin_amdgcn_s_barrier();
    __builtin_amdgcn_s_setprio(1);
    #pragma unroll
    for (int i = 0; i < 4; ++i)
      #pragma unroll
      for (int j = 0; j < 2; ++j)
        acc[i][2 + j] = __builtin_amdgcn_mfma_f32_16x16x32_bf16(af[i], bf1[j], acc[i][2 + j], 0, 0, 0);
    __builtin_amdgcn_s_setprio(0);
    asm volatile("" ::: "memory");
    __builtin_amdgcn_s_barrier();

    // ---- phase 2: af(batch half 1) ; stage B j=0
    #pragma unroll
    for (int i = 0; i < 4; ++i) {
      int row = wm * 128 + 64 + i * 16 + llo;
      af[i] = *reinterpret_cast<const bf16x8*>(sA + ((row * 64 + lhi * 16) ^ kmask));
    }
    if (do_st) stage1(st_slot, kt + 2, 2);
    asm volatile("" ::: "memory");
    __builtin_amdgcn_s_barrier();
    __builtin_amdgcn_s_setprio(1);
    #pragma unroll
    for (int i = 0; i < 4; ++i)
      #pragma unroll
      for (int j = 0; j < 2; ++j)
        acc[4 + i][j] = __builtin_amdgcn_mfma_f32_16x16x32_bf16(af[i], bf0[j], acc[4 + i][j], 0, 0, 0);
    __builtin_amdgcn_s_setprio(0);
    asm volatile("" ::: "memory");
    __builtin_amdgcn_s_barrier();

    // ---- phase 3: (no ds_read) ; stage B j=1 ; boundary wait
    if (do_st) stage1(st_slot, kt + 2, 3);
    __builtin_amdgcn_s_setprio(1);
    #pragma unroll
    for (int i = 0; i < 4; ++i)
      #pragma unroll
      for (int j = 0; j < 2; ++j)
        acc[4 + i][2 + j] = __builtin_amdgcn_mfma_f32_16x16x32_bf16(af[i], bf1[j], acc[4 + i][2 + j], 0, 0, 0);
    __builtin_amdgcn_s_setprio(0);
    if (kt < 14) {
      asm volatile("s_waitcnt vmcnt(4)\n\ts_barrier" ::: "memory");
    } else if (kt == 14) {
      asm volatile("s_waitcnt vmcnt(0)\n\ts_barrier" ::: "memory");
    }
  }

  // ---- epilogue: y[f][b] = relu(fc[b]*acc + bias[f]), float4 over batch
  #pragma unroll
  for (int m = 0; m < 8; ++m) {
    int lb = wm * 128 + m * 16 + lhi * 4;
    float4 fq = *reinterpret_cast<const float4*>(&fcl[lb]);
    #pragma unroll
    for (int n = 0; n < 4; ++n) {
      int fo = fr0 + wn * 64 + n * 16 + llo;
      float bv = bias[fo];
      float4 v;
      v.x = fmaxf(acc[m][n][0] * fq.x + bv, 0.f);
      v.y = fmaxf(acc[m][n][1] * fq.y + bv, 0.f);
      v.z = fmaxf(acc[m][n][2] * fq.z + bv, 0.f);
      v.w = fmaxf(acc[m][n][3] * fq.w + bv, 0.f);
      *reinterpret_cast<float4*>(out + (size_t)fo * BSN + b0 + lb) = v;
    }
  }
}

extern "C" void kernel_launch(void* const* d_in, const int* in_sizes, int n_in,
                              void* d_out, int out_size, void* d_ws, size_t ws_size,
                              hipStream_t stream) {
  (void)in_sizes; (void)n_in; (void)out_size; (void)ws_size;
  const float* x    = (const float*)d_in[0];
  const float* rms  = (const float*)d_in[1];
  const float* wu   = (const float*)d_in[2];
  const float* wl   = (const float*)d_in[3];
  const float* bias = (const float*)d_in[4];
  float* out = (float*)d_out;

  char* ws = (char*)d_ws;
  u16* xbf      = (u16*)ws;                      // 32 MiB  (x^T bf16)
  u16* aprep    = (u16*)(ws + 33554432);         // 4 MiB   (folded weights)
  float* partial = (float*)(ws + 37748736);      // 512 KiB (sumsq partials)

  k_pre<<<2048, 256, 0, stream>>>(x, wu, wl, rms, aprep, xbf, partial);
  k_gemm<<<256, 512, 99328, stream>>>(aprep, xbf, partial, bias, out);
}

// Round 20
// 50.051 us; speedup vs baseline: 1.1722x; 1.0056x over previous
//
#include <hip/hip_runtime.h>

#define DYN 16
#define DON 256
#define DIN 256
#define BSN 4096
#define NF 4096   /* DY*DI feature rows */
#define KTOT 512  /* concat K = 2*DI */

typedef unsigned short u16;
typedef __attribute__((ext_vector_type(8))) short bf16x8;
typedef __attribute__((ext_vector_type(4))) float f32x4;
typedef __attribute__((ext_vector_type(4))) unsigned short u16x4;

static __device__ __forceinline__ u16 f2bf(float f) {
  unsigned u = __builtin_bit_cast(unsigned, f);
  u += 0x7fffu + ((u >> 16) & 1u);
  return (u16)(u >> 16);
}
static __device__ __forceinline__ float bf2f(u16 h) {
  unsigned u = ((unsigned)h) << 16;
  return __builtin_bit_cast(float, u);
}

// ---------------------------------------------------------------------------
// Kernel 1 (fused pre-pass, 2048 blocks) - R19 state (measured 50.3 total):
//  blocks 0..1023: fold rms into weights, concat [Wu | Wl(rev-rms)], bf16.
//  blocks 1024..2047: 128x128 tiled transpose of x w/ f32->bf16 + per-column
//    sum(x^2) partials. LDS XOR swizzle b ^ ((f>>3)<<2): 2-way banks (free),
//    measured -4.4us vs the 4-way stagger.
// ---------------------------------------------------------------------------
__global__ __launch_bounds__(256) void k_pre(
    const float* __restrict__ x, const float* __restrict__ wu,
    const float* __restrict__ wl, const float* __restrict__ rms,
    u16* __restrict__ aprep, u16* __restrict__ xbf,
    float* __restrict__ partial) {
  __shared__ u16 tile[128 * 132];
  const int t = threadIdx.x;
  if (blockIdx.x < 1024) {
    int e = blockIdx.x * 256 + t;
    int row = e >> 6;
    int k0 = (e & 63) << 3;
    int d = row >> 8;
    const float* src;
    const float* rp;
    if (k0 < 256) {
      src = wu + (size_t)row * 256 + k0;
      rp  = rms + d * 256 + k0;
    } else {
      src = wl + (size_t)row * 256 + (k0 - 256);
      rp  = rms + (DYN - 1 - d) * 256 + (k0 - 256);
    }
    float4 s0 = *reinterpret_cast<const float4*>(src);
    float4 s1 = *reinterpret_cast<const float4*>(src + 4);
    float4 r0 = *reinterpret_cast<const float4*>(rp);
    float4 r1 = *reinterpret_cast<const float4*>(rp + 4);
    bf16x8 o;
    o[0] = (short)f2bf(s0.x * r0.x); o[1] = (short)f2bf(s0.y * r0.y);
    o[2] = (short)f2bf(s0.z * r0.z); o[3] = (short)f2bf(s0.w * r0.w);
    o[4] = (short)f2bf(s1.x * r1.x); o[5] = (short)f2bf(s1.y * r1.y);
    o[6] = (short)f2bf(s1.z * r1.z); o[7] = (short)f2bf(s1.w * r1.w);
    *reinterpret_cast<bf16x8*>(aprep + (size_t)row * KTOT + k0) = o;
    return;
  }
  const int bid = blockIdx.x - 1024;
  const int bt = bid & 31, ft = bid >> 5;
  const float* xb = x + (size_t)ft * 128 * BSN + bt * 128;
  const int frow = t >> 5, b4 = (t & 31) * 4;
  #pragma unroll
  for (int p = 0; p < 16; ++p) {
    int f = p * 8 + frow;
    float4 v = *reinterpret_cast<const float4*>(xb + (size_t)f * BSN + b4);
    u16x4 h;
    h[0] = f2bf(v.x); h[1] = f2bf(v.y); h[2] = f2bf(v.z); h[3] = f2bf(v.w);
    *reinterpret_cast<u16x4*>(&tile[f * 132 + (b4 ^ ((f >> 3) << 2))]) = h;
  }
  __syncthreads();
  const int chunk = t & 15;
  const int bg = t >> 4;
  #pragma unroll
  for (int p = 0; p < 8; ++p) {
    int b = bg + p * 16;
    float s = 0.f;
    bf16x8 w;
    #pragma unroll
    for (int j = 0; j < 8; ++j) {
      int r = chunk * 8 + j;
      u16 v = tile[r * 132 + (b ^ ((r >> 3) << 2))];
      float xv = bf2f(v);
      s += xv * xv;
      w[j] = (short)v;
    }
    *reinterpret_cast<bf16x8*>(
        xbf + (size_t)(bt * 128 + b) * NF + ft * 128 + chunk * 8) = w;
    #pragma unroll
    for (int m = 1; m < 16; m <<= 1) s += __shfl_xor(s, m, 64);
    if (chunk == 0) partial[ft * BSN + bt * 128 + b] = s;
  }
}

// ---------------------------------------------------------------------------
// Kernel 2: bf16 MFMA GEMM, R10 structure with the 6 redundant intra-K-step
// barriers REMOVED (only the boundary vmcnt+barrier is load-bearing).
// Correctness: within K-step kt, waves READ slot kt%3 and WRITE (gload_lds)
// slot (kt+2)%3 - disjoint; RAW on slot kt guaranteed by the kt-1 boundary
// (vmcnt(4) retires stage(kt)); WAR on staged slot guaranteed because its
// writes issue only after the boundary barrier following its last reads.
// The intra-step barriers were scheduling rails costing ~6x16x(50-100cy)
// of wave resync at 2 waves/SIMD with nothing to hide it.
// 256 blocks = 1/CU, 8 waves (2Mx4N), wave tile 128x64, BK=32, 16 K-steps,
// 3-slot 32KB ring, boundary s_waitcnt vmcnt(4) (counted - never drains
// mid-loop), involution swizzle (zero-conflict, R2-measured), setprio MFMA
// clusters, fc folded in prologue, float4 batch-contiguous epilogue.
// XCD map: bid&7 = d-pair.
// ---------------------------------------------------------------------------
__global__ __launch_bounds__(512, 2) void k_gemm(
    const u16* __restrict__ aprep, const u16* __restrict__ xbf,
    const float* __restrict__ partial, const float* __restrict__ bias,
    float* __restrict__ out) {
  extern __shared__ char smem[];
  float* fcl = (float*)(smem + 98304);       // 256 floats
  const int bid = blockIdx.x;
  const int dp = bid & 7;                    // d-pair -> XCD
  const int d = ((bid >> 3) & 1) ? (15 - dp) : dp;
  const int bt = bid >> 4;                   // 0..15 batch tile
  const int b0 = bt * 256;
  const int fr0 = d * 256;
  const int t = threadIdx.x;
  const int wave = t >> 6, lane = t & 63;
  const int lhi = lane >> 4, llo = lane & 15;
  const int wm = wave >> 2, wn = wave & 3;   // batch half / feature quarter
  const int kmask = ((llo >> 1) & 7) << 4;

  f32x4 acc[8][4] = {};

  // staging: op 0/1 = A(x) chunk j, op 2/3 = B(W) chunk j-2
  auto stage1 = [&](int slot, int kt, int op) {
    int j = op & 1;
    int c = j * 512 + t;                 // physical 16B chunk (0..1023)
    int cl = c ^ ((c >> 3) & 7);         // logical chunk (involution)
    int r = cl >> 2, kc = cl & 3;
    unsigned lbase = (unsigned)(slot * 32768 + (op >= 2 ? 16384 : 0) +
                                (j * 512 + wave * 64) * 16);
    const u16* g;
    if (op < 2) {
      int fbase = (kt < 8) ? (d * 256 + kt * 32)
                           : ((15 - d) * 256 + (kt - 8) * 32);
      g = xbf + (size_t)(b0 + r) * NF + fbase + kc * 8;
    } else {
      g = aprep + (size_t)(fr0 + r) * KTOT + kt * 32 + kc * 8;
    }
    __builtin_amdgcn_global_load_lds(
        (const __attribute__((address_space(1))) unsigned int*)g,
        (__attribute__((address_space(3))) unsigned int*)(smem + lbase),
        16, 0, 0);
  };
  auto stageK = [&](int slot, int kt) {
    #pragma unroll
    for (int op = 0; op < 4; ++op) stage1(slot, kt, op);
  };

  // fc for this block's 256 batches (overlaps staging latency)
  if (t < 256) {
    float fs = 0.f;
    #pragma unroll
    for (int i = 0; i < 32; ++i) fs += partial[i * BSN + b0 + t];
    fcl[t] = rsqrtf(fs * (1.0f / 4096.0f) + 1e-6f);
  }
  stageK(0, 0);
  stageK(1, 1);
  asm volatile("s_waitcnt vmcnt(4)\n\ts_barrier" ::: "memory");

  for (int kt = 0; kt < 16; ++kt) {
    const int slot = kt % 3;
    const char* sA = (const char*)smem + slot * 32768;
    const char* sB = sA + 16384;
    const int st_slot = (kt + 2) % 3;
    const bool do_st = kt < 14;
    bf16x8 af[4], bf0[2], bf1[2];

    // ---- phase 0: af(batch half 0) + bf0 ; stage A j=0
    #pragma unroll
    for (int i = 0; i < 4; ++i) {
      int row = wm * 128 + i * 16 + llo;
      af[i] = *reinterpret_cast<const bf16x8*>(sA + ((row * 64 + lhi * 16) ^ kmask));
    }
    #pragma unroll
    for (int j = 0; j < 2; ++j) {
      int row = wn * 64 + j * 16 + llo;
      bf0[j] = *reinterpret_cast<const bf16x8*>(sB + ((row * 64 + lhi * 16) ^ kmask));
    }
    if (do_st) stage1(st_slot, kt + 2, 0);
    __builtin_amdgcn_s_setprio(1);
    #pragma unroll
    for (int i = 0; i < 4; ++i)
      #pragma unroll
      for (int j = 0; j < 2; ++j)
        acc[i][j] = __builtin_amdgcn_mfma_f32_16x16x32_bf16(af[i], bf0[j], acc[i][j], 0, 0, 0);
    __builtin_amdgcn_s_setprio(0);

    // ---- phase 1: bf1 ; stage A j=1
    #pragma unroll
    for (int j = 0; j < 2; ++j) {
      int row = wn * 64 + 32 + j * 16 + llo;
      bf1[j] = *reinterpret_cast<const bf16x8*>(sB + ((row * 64 + lhi * 16) ^ kmask));
    }
    if (do_st) stage1(st_slot, kt + 2, 1);
    __builtin_amdgcn_s_setprio(1);
    #pragma unroll
    for (int i = 0; i < 4; ++i)
      #pragma unroll
      for (int j = 0; j < 2; ++j)
        acc[i][2 + j] = __builtin_amdgcn_mfma_f32_16x16x32_bf16(af[i], bf1[j], acc[i][2 + j], 0, 0, 0);
    __builtin_amdgcn_s_setprio(0);

    // ---- phase 2: af(batch half 1) ; stage B j=0
    #pragma unroll
    for (int i = 0; i < 4; ++i) {
      int row = wm * 128 + 64 + i * 16 + llo;
      af[i] = *reinterpret_cast<const bf16x8*>(sA + ((row * 64 + lhi * 16) ^ kmask));
    }
    if (do_st) stage1(st_slot, kt + 2, 2);
    __builtin_amdgcn_s_setprio(1);
    #pragma unroll
    for (int i = 0; i < 4; ++i)
      #pragma unroll
      for (int j = 0; j < 2; ++j)
        acc[4 + i][j] = __builtin_amdgcn_mfma_f32_16x16x32_bf16(af[i], bf0[j], acc[4 + i][j], 0, 0, 0);
    __builtin_amdgcn_s_setprio(0);

    // ---- phase 3: (no ds_read) ; stage B j=1 ; boundary wait
    if (do_st) stage1(st_slot, kt + 2, 3);
    __builtin_amdgcn_s_setprio(1);
    #pragma unroll
    for (int i = 0; i < 4; ++i)
      #pragma unroll
      for (int j = 0; j < 2; ++j)
        acc[4 + i][2 + j] = __builtin_amdgcn_mfma_f32_16x16x32_bf16(af[i], bf1[j], acc[4 + i][2 + j], 0, 0, 0);
    __builtin_amdgcn_s_setprio(0);
    if (kt < 14) {
      asm volatile("s_waitcnt vmcnt(4)\n\ts_barrier" ::: "memory");
    } else if (kt == 14) {
      asm volatile("s_waitcnt vmcnt(0)\n\ts_barrier" ::: "memory");
    }
  }

  // ---- epilogue: y[f][b] = relu(fc[b]*acc + bias[f]), float4 over batch
  #pragma unroll
  for (int m = 0; m < 8; ++m) {
    int lb = wm * 128 + m * 16 + lhi * 4;
    float4 fq = *reinterpret_cast<const float4*>(&fcl[lb]);
    #pragma unroll
    for (int n = 0; n < 4; ++n) {
      int fo = fr0 + wn * 64 + n * 16 + llo;
      float bv = bias[fo];
      float4 v;
      v.x = fmaxf(acc[m][n][0] * fq.x + bv, 0.f);
      v.y = fmaxf(acc[m][n][1] * fq.y + bv, 0.f);
      v.z = fmaxf(acc[m][n][2] * fq.z + bv, 0.f);
      v.w = fmaxf(acc[m][n][3] * fq.w + bv, 0.f);
      *reinterpret_cast<float4*>(out + (size_t)fo * BSN + b0 + lb) = v;
    }
  }
}

extern "C" void kernel_launch(void* const* d_in, const int* in_sizes, int n_in,
                              void* d_out, int out_size, void* d_ws, size_t ws_size,
                              hipStream_t stream) {
  (void)in_sizes; (void)n_in; (void)out_size; (void)ws_size;
  const float* x    = (const float*)d_in[0];
  const float* rms  = (const float*)d_in[1];
  const float* wu   = (const float*)d_in[2];
  const float* wl   = (const float*)d_in[3];
  const float* bias = (const float*)d_in[4];
  float* out = (float*)d_out;

  char* ws = (char*)d_ws;
  u16* xbf      = (u16*)ws;                      // 32 MiB  (x^T bf16)
  u16* aprep    = (u16*)(ws + 33554432);         // 4 MiB   (folded weights)
  float* partial = (float*)(ws + 37748736);      // 512 KiB (sumsq partials)

  k_pre<<<2048, 256, 0, stream>>>(x, wu, wl, rms, aprep, xbf, partial);
  k_gemm<<<256, 512, 99328, stream>>>(aprep, xbf, partial, bias, out);
}